// Round 7
// baseline (800.775 us; speedup 1.0000x reference)
//
#include <hip/hip_runtime.h>
#include <math.h>

// EGCL_Multi on MFMA, barrier-free, spill-free, occupancy-tuned edge kernel.
// N=512 nodes, NH=8 heads, HD=128, M=256.
#define N_NODES 512
#define NH 8
#define HD 128
#define M 256
#define PITCH 264        // LDS activation row pitch in bf16 (528B)
#define JTILE 64         // edges (j) per block = 4 waves x 16
#define RPW 16           // rows per wave

typedef __bf16 v8bf __attribute__((ext_vector_type(8)));
typedef float f32x4 __attribute__((ext_vector_type(4)));
typedef unsigned short us4v __attribute__((ext_vector_type(4)));

__device__ __forceinline__ float silu_f(float v) { return v / (1.f + __expf(-v)); }
__device__ __forceinline__ unsigned short f2bf(float f) {
  unsigned u = __float_as_uint(f);
  u += 0x7fffu + ((u >> 16) & 1u);
  return (unsigned short)(u >> 16);
}
__device__ __forceinline__ float bf2f(unsigned short s) {
  return __uint_as_float(((unsigned)s) << 16);
}

// ---------------------------------------------------------------------------
// Weight prep: fp32 [K,N] row-major -> bf16 MFMA-B-fragment order.
// dst[((kt*16 + nt)*64 + lane)*8 + j] = W[kt*32 + (lane>>4)*8 + j][nt*16 + (lane&15)]
// We1 @0, Wx0 @65536, Wx1 @131072, Wxo (256x8 pad->16) @196608.
// ---------------------------------------------------------------------------
__global__ __launch_bounds__(256) void k_prep(
    const float* __restrict__ We1, const float* __restrict__ Wx0,
    const float* __restrict__ Wx1, const float* __restrict__ Wxo,
    unsigned short* __restrict__ wsB)
{
  const int gid = blockIdx.x * 256 + threadIdx.x;
  if (gid >= 200704) return;
  float val;
  if (gid < 196608) {
    const int layer = gid >> 16;
    const int i2 = gid & 65535;
    const int j = i2 & 7, lane = (i2 >> 3) & 63, nt = (i2 >> 9) & 15, kt = i2 >> 13;
    const int k = kt * 32 + (lane >> 4) * 8 + j;
    const int n = nt * 16 + (lane & 15);
    const float* W = (layer == 0) ? We1 : (layer == 1) ? Wx0 : Wx1;
    val = W[k * 256 + n];
  } else {
    const int i2 = gid - 196608;
    const int j = i2 & 7, lane = (i2 >> 3) & 63, kt = (i2 >> 9) & 7;
    const int k = kt * 32 + (lane >> 4) * 8 + j;
    const int n = lane & 15;
    val = (n < 8) ? Wxo[k * 8 + n] : 0.f;
  }
  wsB[gid] = f2bf(val);
}

// ---------------------------------------------------------------------------
// Per-node P/Q precompute (layer-0 algebraic split), fp32.
// ---------------------------------------------------------------------------
__global__ __launch_bounds__(256) void k_pq(
    const float* __restrict__ x, const float* __restrict__ h,
    const float* __restrict__ We0,
    float* __restrict__ P, float* __restrict__ Q)
{
  const int i = blockIdx.x, t = threadIdx.x;
  __shared__ float s_x[24];
  __shared__ float s_hc[192];
  if (t < 24) s_x[t] = x[i * 24 + t];
  __syncthreads();
  if (t < HD) {
    s_hc[t] = h[i * HD + t];
  } else if (t < 192) {
    const int p = t - HD, a = p >> 3, b = p & 7;
    float s = 0.f;
#pragma unroll
    for (int d = 0; d < 3; ++d) {
      const float dx = s_x[a * 3 + d] - s_x[b * 3 + d];
      s = fmaf(dx, dx, s);
    }
    s_hc[t] = s;
  }
  __syncthreads();
  float p = 0.f, q = 0.f;
  for (int k = 0; k < 192; ++k) {
    const float hv = s_hc[k];
    p = fmaf(hv, We0[(8 + k) * M + t], p);
    q = fmaf(hv, We0[(200 + k) * M + t], q);
  }
  P[i * M + t] = p;
  Q[i * M + t] = q;
}

// ---------------------------------------------------------------------------
// Fused edge pipeline: zero barriers, wave-private rows, single LDS buffer.
// Each 256-wide GEMM runs as two 8-nt passes (acc = 32 regs). Pass-0 output is
// STAGED IN REGISTERS (packed bf16) until pass-1's A-reads finish, then both
// halves flush to LDS — no in-place hazard, no second buffer.
// __launch_bounds__(256,3): ~170 regs/wave — fits ~130 peak live, no spill,
// 3 waves/SIMD (R6's (256,4)=128-reg cap spilled 1.2 GB to scratch).
// ---------------------------------------------------------------------------
__global__ __launch_bounds__(256, 3) void k_edge(
    const float* __restrict__ x,
    const float* __restrict__ P, const float* __restrict__ Q,
    const float* __restrict__ We0, const float* __restrict__ be0,
    const float* __restrict__ be1,
    const float* __restrict__ Winf, const float* __restrict__ binf,
    const float* __restrict__ bx0, const float* __restrict__ bx1,
    const float* __restrict__ bxo,
    const unsigned short* __restrict__ wsB,
    float* __restrict__ mi_acc, float* __restrict__ shift_acc)
{
  const int i  = blockIdx.x;
  const int j0 = blockIdx.y * JTILE;
  const int t  = threadIdx.x;
  const int lane = t & 63, wave = t >> 6;
  const int lnib = lane & 15, quad = lane >> 4;
  const int r0 = wave * RPW;       // block-local row base
  const int jw = j0 + r0;          // first edge (j) of this wave

  __shared__ __align__(16) unsigned short a_act[JTILE * PITCH];  // 33.8 KB
  __shared__ __align__(16) float s_sqn[JTILE][8];                // 2 KB
  __shared__ float s_e[JTILE];                                   // 256 B

  // ---- sqn for this wave's 16 rows (wave-private LDS region) ----
#pragma unroll
  for (int kk = 0; kk < 2; ++kk) {
    const int idx = kk * 64 + lane;          // 0..127 = 16 rows x 8 heads
    const int r = idx >> 3, hh = idx & 7;
    const int j = jw + r;
    float s = 0.f;
#pragma unroll
    for (int d = 0; d < 3; ++d) {
      const float dx = x[j * 24 + hh * 3 + d] - x[i * 24 + hh * 3 + d];
      s = fmaf(dx, dx, s);
    }
    s_sqn[r0 + r][hh] = s;
  }

  // ---- stage 0: a1 = silu(be0 + Q[i] + P[j] + sqn . We0[0:8]) -> LDS bf16 ----
  {
    const int c0 = lane * 4;                 // 64 lanes x 4 = 256 channels
    const f32x4 qv = *(const f32x4*)&Q[i * M + c0];
    const f32x4 b0 = *(const f32x4*)&be0[c0];
    const f32x4 base = qv + b0;
    f32x4 w0k[8];
#pragma unroll
    for (int k = 0; k < 8; ++k) w0k[k] = *(const f32x4*)&We0[k * M + c0];
#pragma unroll 4
    for (int r = 0; r < RPW; ++r) {
      const f32x4 pv = *(const f32x4*)&P[(jw + r) * M + c0];
      f32x4 a = base + pv;
#pragma unroll
      for (int k = 0; k < 8; ++k) {
        const float sv = s_sqn[r0 + r][k];   // broadcast
        a[0] = fmaf(sv, w0k[k][0], a[0]);
        a[1] = fmaf(sv, w0k[k][1], a[1]);
        a[2] = fmaf(sv, w0k[k][2], a[2]);
        a[3] = fmaf(sv, w0k[k][3], a[3]);
      }
      us4v pk;
      pk[0] = f2bf(silu_f(a[0])); pk[1] = f2bf(silu_f(a[1]));
      pk[2] = f2bf(silu_f(a[2])); pk[3] = f2bf(silu_f(a[3]));
      *(us4v*)&a_act[(r0 + r) * PITCH + c0] = pk;
    }
  }

  const float binf0 = binf[0];

  f32x4 acc[8];                              // 32 floats

  // 8-nt half-GEMM over nt = ntb..ntb+7; A = this wave's 16 LDS rows
  auto run_gemm8 = [&](const unsigned short* __restrict__ B, int ntb) {
#pragma unroll
    for (int kt = 0; kt < 8; ++kt) {
      const v8bf a0 = *(const v8bf*)&a_act[(r0 + lnib) * PITCH + kt * 32 + quad * 8];
#pragma unroll
      for (int n = 0; n < 8; ++n) {
        const v8bf bv = *(const v8bf*)&B[((kt * 16 + ntb + n) * 64 + lane) * 8];
        acc[n] = __builtin_amdgcn_mfma_f32_16x16x32_bf16(a0, bv, acc[n], 0, 0, 0);
      }
    }
  };

  // Staged in-place GEMM: out = silu(A @ W + b), A and out share a_act rows.
  // Pass-0 results held packed in regs until pass-1's MFMA (last A-read) done.
  auto gemm_silu_staged = [&](const unsigned short* __restrict__ B,
                              const float* __restrict__ bias) {
    us4v save[8];
#pragma unroll
    for (int n = 0; n < 8; ++n) {
      const float b = bias[n * 16 + lnib];
      acc[n] = (f32x4){b, b, b, b};
    }
    run_gemm8(B, 0);
#pragma unroll
    for (int n = 0; n < 8; ++n) {
      us4v pk;
#pragma unroll
      for (int reg = 0; reg < 4; ++reg) pk[reg] = f2bf(silu_f(acc[n][reg]));
      save[n] = pk;
    }
#pragma unroll
    for (int n = 0; n < 8; ++n) {
      const float b = bias[(8 + n) * 16 + lnib];
      acc[n] = (f32x4){b, b, b, b};
    }
    run_gemm8(B, 8);                         // last read of A
#pragma unroll
    for (int n = 0; n < 8; ++n)
#pragma unroll
      for (int reg = 0; reg < 4; ++reg) {
        const int row = r0 + quad * 4 + reg;
        a_act[row * PITCH + (8 + n) * 16 + lnib] = f2bf(silu_f(acc[n][reg]));
      }
#pragma unroll
    for (int n = 0; n < 8; ++n)
#pragma unroll
      for (int reg = 0; reg < 4; ++reg) {
        const int row = r0 + quad * 4 + reg;
        a_act[row * PITCH + n * 16 + lnib] = save[n][reg];
      }
  };

  // ===== GEMM1: m = silu(a1 @ We1 + be1), diag mask + gate fused, staged =====
  {
    float ge[4] = {0.f, 0.f, 0.f, 0.f};
    us4v save[8];
    // pass 0 (cols 0..127): stage in regs
#pragma unroll
    for (int n = 0; n < 8; ++n) {
      const float b = be1[n * 16 + lnib];
      acc[n] = (f32x4){b, b, b, b};
    }
    run_gemm8(wsB, 0);
#pragma unroll
    for (int n = 0; n < 8; ++n) {
      const float wfv = Winf[n * 16 + lnib];
      us4v pk;
#pragma unroll
      for (int reg = 0; reg < 4; ++reg) {
        float v = silu_f(acc[n][reg]);
        if (j0 + r0 + quad * 4 + reg == i) v = 0.f;
        ge[reg] = fmaf(v, wfv, ge[reg]);
        pk[reg] = f2bf(v);
      }
      save[n] = pk;
    }
    // pass 1 (cols 128..255)
#pragma unroll
    for (int n = 0; n < 8; ++n) {
      const float b = be1[(8 + n) * 16 + lnib];
      acc[n] = (f32x4){b, b, b, b};
    }
    run_gemm8(wsB, 8);                       // last read of a1
#pragma unroll
    for (int n = 0; n < 8; ++n) {
      const float wfv = Winf[(8 + n) * 16 + lnib];
#pragma unroll
      for (int reg = 0; reg < 4; ++reg) {
        float v = silu_f(acc[n][reg]);
        const int row = r0 + quad * 4 + reg;
        if (j0 + row == i) v = 0.f;
        ge[reg] = fmaf(v, wfv, ge[reg]);
        a_act[row * PITCH + (8 + n) * 16 + lnib] = f2bf(v);
      }
    }
    // flush staged pass-0 (m cols 0..127)
#pragma unroll
    for (int n = 0; n < 8; ++n)
#pragma unroll
      for (int reg = 0; reg < 4; ++reg) {
        const int row = r0 + quad * 4 + reg;
        a_act[row * PITCH + n * 16 + lnib] = save[n][reg];
      }
    // gate: butterfly over 16 lnib lanes
#pragma unroll
    for (int reg = 0; reg < 4; ++reg) {
      float g = ge[reg];
      g += __shfl_xor(g, 1);
      g += __shfl_xor(g, 2);
      g += __shfl_xor(g, 4);
      g += __shfl_xor(g, 8);
      const float ev = 1.f / (1.f + __expf(-(g + binf0)));
      if (lnib == 0) s_e[r0 + quad * 4 + reg] = ev;
    }
  }

  // ===== mi: wave-private LDS re-read of m, scaled by e[r] =====
  {
    const int c0 = lane * 4;
    f32x4 mip = (f32x4){0.f, 0.f, 0.f, 0.f};
#pragma unroll
    for (int r = 0; r < RPW; ++r) {
      const us4v mv = *(const us4v*)&a_act[(r0 + r) * PITCH + c0];
      const float ev = s_e[r0 + r];          // broadcast
      mip[0] = fmaf(bf2f(mv[0]), ev, mip[0]);
      mip[1] = fmaf(bf2f(mv[1]), ev, mip[1]);
      mip[2] = fmaf(bf2f(mv[2]), ev, mip[2]);
      mip[3] = fmaf(bf2f(mv[3]), ev, mip[3]);
    }
    atomicAdd(&mi_acc[i * M + c0 + 0], mip[0]);
    atomicAdd(&mi_acc[i * M + c0 + 1], mip[1]);
    atomicAdd(&mi_acc[i * M + c0 + 2], mip[2]);
    atomicAdd(&mi_acc[i * M + c0 + 3], mip[3]);
  }

  // ===== GEMM2: a2 = silu(m @ Wx0 + bx0), staged in-place =====
  gemm_silu_staged(wsB + 65536, bx0);

  // ===== GEMM3: a3 = silu(a2 @ Wx1 + bx1), staged in-place =====
  gemm_silu_staged(wsB + 131072, bx1);

  // ===== GEMM4: px = a3 @ Wxo + bxo (N padded to 16; cols 8..15 zero) =====
  f32x4 px;
  {
    const float b = (lnib < 8) ? bxo[lnib] : 0.f;
    px = (f32x4){b, b, b, b};
    const unsigned short* B = wsB + 196608;
#pragma unroll
    for (int kt = 0; kt < 8; ++kt) {
      const v8bf a0 = *(const v8bf*)&a_act[(r0 + lnib) * PITCH + kt * 32 + quad * 8];
      const v8bf bv = *(const v8bf*)&B[(kt * 64 + lane) * 8];
      px = __builtin_amdgcn_mfma_f32_16x16x32_bf16(a0, bv, px, 0, 0, 0);
    }
  }

  // ===== shift: per-head normalized coordinate aggregation (wave-local) =====
  {
    const int hh = lnib & 7;   // lanes lnib>=8 hold zero px (padded B cols)
    const float xi0 = x[i * 24 + hh * 3 + 0];
    const float xi1 = x[i * 24 + hh * 3 + 1];
    const float xi2 = x[i * 24 + hh * 3 + 2];
    float p0 = 0.f, p1 = 0.f, p2 = 0.f;
#pragma unroll
    for (int reg = 0; reg < 4; ++reg) {
      const int row = r0 + quad * 4 + reg;
      const int jg = j0 + row;
      if (jg != i) {
        const float pxv = px[reg];
        const float sq  = s_sqn[row][hh];
        const float f   = pxv / (sqrtf(sq + 1e-8f) + 1.f);  // NORM_CONST=1
        p0 = fmaf(x[jg * 24 + hh * 3 + 0] - xi0, f, p0);
        p1 = fmaf(x[jg * 24 + hh * 3 + 1] - xi1, f, p1);
        p2 = fmaf(x[jg * 24 + hh * 3 + 2] - xi2, f, p2);
      }
    }
    p0 += __shfl_xor(p0, 16); p0 += __shfl_xor(p0, 32);
    p1 += __shfl_xor(p1, 16); p1 += __shfl_xor(p1, 32);
    p2 += __shfl_xor(p2, 16); p2 += __shfl_xor(p2, 32);
    if (lane < 8) {
      atomicAdd(&shift_acc[i * 24 + hh * 3 + 0], p0);
      atomicAdd(&shift_acc[i * 24 + hh * 3 + 1], p1);
      atomicAdd(&shift_acc[i * 24 + hh * 3 + 2], p2);
    }
  }
}

// ---------------------------------------------------------------------------
__global__ void k_xout(const float* __restrict__ x, const float* __restrict__ shift,
                       float* __restrict__ out)
{
  const int idx = blockIdx.x * 256 + threadIdx.x;
  if (idx < N_NODES * NH * 3) out[idx] = x[idx] + shift[idx] * (1.f / 511.f);
}

__global__ __launch_bounds__(256) void k_hout(
    const float* __restrict__ h, const float* __restrict__ mi,
    const float* __restrict__ Wh0, const float* __restrict__ bh0,
    const float* __restrict__ Wh1, const float* __restrict__ bh1,
    const float* __restrict__ Who, const float* __restrict__ bho,
    float* __restrict__ out)
{
  const int i = blockIdx.x, t = threadIdx.x;
  __shared__ float s_in[M + HD];
  __shared__ float s_b[M];
  s_in[t] = mi[i * M + t];
  if (t < HD) s_in[M + t] = h[i * HD + t];
  __syncthreads();
  float acc = bh0[t];
  for (int k = 0; k < M + HD; ++k) acc = fmaf(s_in[k], Wh0[k * M + t], acc);
  s_b[t] = silu_f(acc);
  __syncthreads();
  float acc2 = bh1[t];
  for (int k = 0; k < M; ++k) acc2 = fmaf(s_b[k], Wh1[k * M + t], acc2);
  const float a1v = silu_f(acc2);
  __syncthreads();
  s_in[t] = a1v;
  __syncthreads();
  if (t < HD) {
    float o = bho[t];
    for (int k = 0; k < M; ++k) o = fmaf(s_in[k], Who[k * HD + t], o);
    out[i * HD + t] = h[i * HD + t] + o;
  }
}

// ---------------------------------------------------------------------------
extern "C" void kernel_launch(void* const* d_in, const int* in_sizes, int n_in,
                              void* d_out, int out_size, void* d_ws, size_t ws_size,
                              hipStream_t stream)
{
  const float* x    = (const float*)d_in[0];
  const float* h    = (const float*)d_in[1];
  const float* We0  = (const float*)d_in[2];
  const float* be0  = (const float*)d_in[3];
  const float* We1  = (const float*)d_in[4];
  const float* be1  = (const float*)d_in[5];
  const float* Winf = (const float*)d_in[6];
  const float* binf = (const float*)d_in[7];
  const float* Wx0  = (const float*)d_in[8];
  const float* bx0  = (const float*)d_in[9];
  const float* Wx1  = (const float*)d_in[10];
  const float* bx1  = (const float*)d_in[11];
  const float* Wxo  = (const float*)d_in[12];
  const float* bxo  = (const float*)d_in[13];
  const float* Wh0  = (const float*)d_in[14];
  const float* bh0  = (const float*)d_in[15];
  const float* Wh1  = (const float*)d_in[16];
  const float* bh1  = (const float*)d_in[17];
  const float* Who  = (const float*)d_in[18];
  const float* bho  = (const float*)d_in[19];

  float* out_x = (float*)d_out;                 // [512,8,3]
  float* out_h = out_x + N_NODES * NH * 3;      // [512,128]

  // ws layout (float units): mi[131072] | shift[12288] | P[131072] | Q[131072] | wsB(bf16)
  float* ws    = (float*)d_ws;
  float* mi    = ws;
  float* shift = ws + 131072;
  float* P     = ws + 143360;
  float* Q     = ws + 274432;
  unsigned short* wsB = (unsigned short*)(ws + 405504);

  hipMemsetAsync(mi, 0, (131072 + 12288) * sizeof(float), stream);

  k_prep<<<784, 256, 0, stream>>>(We1, Wx0, Wx1, Wxo, wsB);
  k_pq<<<N_NODES, 256, 0, stream>>>(x, h, We0, P, Q);
  k_edge<<<dim3(N_NODES, N_NODES / JTILE), 256, 0, stream>>>(
      x, P, Q, We0, be0, be1, Winf, binf, bx0, bx1, bxo, wsB, mi, shift);
  k_xout<<<(N_NODES * NH * 3 + 255) / 256, 256, 0, stream>>>(x, shift, out_x);
  k_hout<<<N_NODES, 256, 0, stream>>>(h, mi, Wh0, bh0, Wh1, bh1, Who, bho, out_h);
}

// Round 8
// 356.927 us; speedup vs baseline: 2.2435x; 2.2435x over previous
//
#include <hip/hip_runtime.h>
#include <math.h>

// EGCL_Multi on MFMA. Edge kernel: wave-private GEMM rows, acc[16] (no staged
// register save), B-matrix staged per-kt into LDS via global_load_lds (no VGPR
// round-trip, shrinks the B prefetch window that caused R6/R7 scratch spills).
// N=512 nodes, NH=8 heads, HD=128, M=256.
#define N_NODES 512
#define NH 8
#define HD 128
#define M 256
#define PITCH 264        // LDS activation row pitch in bf16 (528B)
#define JTILE 64         // edges (j) per block = 4 waves x 16
#define RPW 16           // rows per wave

typedef __bf16 v8bf __attribute__((ext_vector_type(8)));
typedef float f32x4 __attribute__((ext_vector_type(4)));
typedef unsigned short us4v __attribute__((ext_vector_type(4)));

__device__ __forceinline__ float silu_f(float v) { return v / (1.f + __expf(-v)); }
__device__ __forceinline__ unsigned short f2bf(float f) {
  unsigned u = __float_as_uint(f);
  u += 0x7fffu + ((u >> 16) & 1u);
  return (unsigned short)(u >> 16);
}
__device__ __forceinline__ float bf2f(unsigned short s) {
  return __uint_as_float(((unsigned)s) << 16);
}

// async global->LDS, 16B per lane. lds base is wave-uniform; HW writes lane i
// to base + i*16 (m104/m108 semantics). src is per-lane (base + lane*16).
__device__ __forceinline__ void gl2lds16(const unsigned short* g, unsigned short* l) {
  __builtin_amdgcn_global_load_lds(
      (const __attribute__((address_space(1))) unsigned int*)g,
      (__attribute__((address_space(3))) unsigned int*)l, 16, 0, 0);
}

// ---------------------------------------------------------------------------
// Weight prep: fp32 [K,N] row-major -> bf16 MFMA-B-fragment order.
// dst[((kt*16 + nt)*64 + lane)*8 + j] = W[kt*32 + (lane>>4)*8 + j][nt*16 + (lane&15)]
// We1 @0, Wx0 @65536, Wx1 @131072, Wxo (256x8 pad->16) @196608.
// ---------------------------------------------------------------------------
__global__ __launch_bounds__(256) void k_prep(
    const float* __restrict__ We1, const float* __restrict__ Wx0,
    const float* __restrict__ Wx1, const float* __restrict__ Wxo,
    unsigned short* __restrict__ wsB)
{
  const int gid = blockIdx.x * 256 + threadIdx.x;
  if (gid >= 200704) return;
  float val;
  if (gid < 196608) {
    const int layer = gid >> 16;
    const int i2 = gid & 65535;
    const int j = i2 & 7, lane = (i2 >> 3) & 63, nt = (i2 >> 9) & 15, kt = i2 >> 13;
    const int k = kt * 32 + (lane >> 4) * 8 + j;
    const int n = nt * 16 + (lane & 15);
    const float* W = (layer == 0) ? We1 : (layer == 1) ? Wx0 : Wx1;
    val = W[k * 256 + n];
  } else {
    const int i2 = gid - 196608;
    const int j = i2 & 7, lane = (i2 >> 3) & 63, kt = (i2 >> 9) & 7;
    const int k = kt * 32 + (lane >> 4) * 8 + j;
    const int n = lane & 15;
    val = (n < 8) ? Wxo[k * 8 + n] : 0.f;
  }
  wsB[gid] = f2bf(val);
}

// ---------------------------------------------------------------------------
// Per-node P/Q precompute (layer-0 algebraic split), fp32.
// ---------------------------------------------------------------------------
__global__ __launch_bounds__(256) void k_pq(
    const float* __restrict__ x, const float* __restrict__ h,
    const float* __restrict__ We0,
    float* __restrict__ P, float* __restrict__ Q)
{
  const int i = blockIdx.x, t = threadIdx.x;
  __shared__ float s_x[24];
  __shared__ float s_hc[192];
  if (t < 24) s_x[t] = x[i * 24 + t];
  __syncthreads();
  if (t < HD) {
    s_hc[t] = h[i * HD + t];
  } else if (t < 192) {
    const int p = t - HD, a = p >> 3, b = p & 7;
    float s = 0.f;
#pragma unroll
    for (int d = 0; d < 3; ++d) {
      const float dx = s_x[a * 3 + d] - s_x[b * 3 + d];
      s = fmaf(dx, dx, s);
    }
    s_hc[t] = s;
  }
  __syncthreads();
  float p = 0.f, q = 0.f;
  for (int k = 0; k < 192; ++k) {
    const float hv = s_hc[k];
    p = fmaf(hv, We0[(8 + k) * M + t], p);
    q = fmaf(hv, We0[(200 + k) * M + t], q);
  }
  P[i * M + t] = p;
  Q[i * M + t] = q;
}

// ---------------------------------------------------------------------------
// Fused edge pipeline. Block = (i, 64-j tile); wave w owns rows [16w,16w+16).
// Per-kt B staging: sync -> global_load_lds 16KB -> sync -> ds_read frags.
// ---------------------------------------------------------------------------
__global__ __launch_bounds__(256, 3) void k_edge(
    const float* __restrict__ x,
    const float* __restrict__ P, const float* __restrict__ Q,
    const float* __restrict__ We0, const float* __restrict__ be0,
    const float* __restrict__ be1,
    const float* __restrict__ Winf, const float* __restrict__ binf,
    const float* __restrict__ bx0, const float* __restrict__ bx1,
    const float* __restrict__ bxo,
    const unsigned short* __restrict__ wsB,
    float* __restrict__ mi_acc, float* __restrict__ shift_acc)
{
  const int i  = blockIdx.x;
  const int j0 = blockIdx.y * JTILE;
  const int t  = threadIdx.x;
  const int lane = t & 63, wave = t >> 6;
  const int lnib = lane & 15, quad = lane >> 4;
  const int r0 = wave * RPW;       // block-local row base
  const int jw = j0 + r0;          // first edge (j) of this wave

  __shared__ __align__(16) unsigned short a_act[JTILE * PITCH];  // 33.8 KB
  __shared__ __align__(16) unsigned short B_buf[8192];           // 16 KB (one kt slice)
  __shared__ __align__(16) float s_sqn[JTILE][8];                // 2 KB
  __shared__ float s_e[JTILE];                                   // 256 B

  // ---- sqn for this wave's 16 rows (wave-private LDS region) ----
#pragma unroll
  for (int kk = 0; kk < 2; ++kk) {
    const int idx = kk * 64 + lane;          // 0..127 = 16 rows x 8 heads
    const int r = idx >> 3, hh = idx & 7;
    const int j = jw + r;
    float s = 0.f;
#pragma unroll
    for (int d = 0; d < 3; ++d) {
      const float dx = x[j * 24 + hh * 3 + d] - x[i * 24 + hh * 3 + d];
      s = fmaf(dx, dx, s);
    }
    s_sqn[r0 + r][hh] = s;
  }

  // ---- stage 0: a1 = silu(be0 + Q[i] + P[j] + sqn . We0[0:8]) -> LDS bf16 ----
  {
    const int c0 = lane * 4;                 // 64 lanes x 4 = 256 channels
    const f32x4 qv = *(const f32x4*)&Q[i * M + c0];
    const f32x4 b0 = *(const f32x4*)&be0[c0];
    const f32x4 base = qv + b0;
    f32x4 w0k[8];
#pragma unroll
    for (int k = 0; k < 8; ++k) w0k[k] = *(const f32x4*)&We0[k * M + c0];
#pragma unroll 4
    for (int r = 0; r < RPW; ++r) {
      const f32x4 pv = *(const f32x4*)&P[(jw + r) * M + c0];
      f32x4 a = base + pv;
#pragma unroll
      for (int k = 0; k < 8; ++k) {
        const float sv = s_sqn[r0 + r][k];   // broadcast
        a[0] = fmaf(sv, w0k[k][0], a[0]);
        a[1] = fmaf(sv, w0k[k][1], a[1]);
        a[2] = fmaf(sv, w0k[k][2], a[2]);
        a[3] = fmaf(sv, w0k[k][3], a[3]);
      }
      us4v pk;
      pk[0] = f2bf(silu_f(a[0])); pk[1] = f2bf(silu_f(a[1]));
      pk[2] = f2bf(silu_f(a[2])); pk[3] = f2bf(silu_f(a[3]));
      *(us4v*)&a_act[(r0 + r) * PITCH + c0] = pk;
    }
  }

  const float binf0 = binf[0];

  f32x4 acc[16];                             // 64 floats -> AGPRs

  // Full 16-nt GEMM over this wave's 16 rows; B staged per-kt through LDS.
  // Bg = pre-swizzled weight base for this layer (short units).
  auto run_gemm = [&](const unsigned short* __restrict__ Bg) {
#pragma unroll
    for (int kt = 0; kt < 8; ++kt) {
      __syncthreads();                       // all waves done with prior slice
      {
        const unsigned short* src = Bg + kt * 8192 + wave * 2048 + lane * 8;
        unsigned short* dst = &B_buf[wave * 2048];   // wave-uniform base
        gl2lds16(src,        dst);
        gl2lds16(src + 512,  dst + 512);
        gl2lds16(src + 1024, dst + 1024);
        gl2lds16(src + 1536, dst + 1536);
      }
      __syncthreads();                       // staging complete
      const v8bf a0 = *(const v8bf*)&a_act[(r0 + lnib) * PITCH + kt * 32 + quad * 8];
#pragma unroll
      for (int nt = 0; nt < 16; ++nt) {
        const v8bf bv = *(const v8bf*)&B_buf[nt * 512 + lane * 8];
        acc[nt] = __builtin_amdgcn_mfma_f32_16x16x32_bf16(a0, bv, acc[nt], 0, 0, 0);
      }
    }
  };

  // ===== GEMM1: m = silu(a1 @ We1 + be1), diag mask, gate =====
#pragma unroll
  for (int nt = 0; nt < 16; ++nt) {
    const float b = be1[nt * 16 + lnib];
    acc[nt] = (f32x4){b, b, b, b};
  }
  run_gemm(wsB);
  {
    float ge[4] = {0.f, 0.f, 0.f, 0.f};
#pragma unroll
    for (int nt = 0; nt < 16; ++nt) {
      const float wfv = Winf[nt * 16 + lnib];
#pragma unroll
      for (int reg = 0; reg < 4; ++reg) {
        float v = silu_f(acc[nt][reg]);
        const int row = r0 + quad * 4 + reg;
        if (j0 + row == i) v = 0.f;
        a_act[row * PITCH + nt * 16 + lnib] = f2bf(v);
        ge[reg] = fmaf(v, wfv, ge[reg]);
      }
    }
#pragma unroll
    for (int reg = 0; reg < 4; ++reg) {
      float g = ge[reg];
      g += __shfl_xor(g, 1);
      g += __shfl_xor(g, 2);
      g += __shfl_xor(g, 4);
      g += __shfl_xor(g, 8);
      const float ev = 1.f / (1.f + __expf(-(g + binf0)));
      if (lnib == 0) s_e[r0 + quad * 4 + reg] = ev;
    }
  }

  // ===== mi: wave-private LDS re-read of m, scaled by e[r] =====
  {
    const int c0 = lane * 4;
    f32x4 mip = (f32x4){0.f, 0.f, 0.f, 0.f};
#pragma unroll
    for (int r = 0; r < RPW; ++r) {
      const us4v mv = *(const us4v*)&a_act[(r0 + r) * PITCH + c0];
      const float ev = s_e[r0 + r];          // broadcast
      mip[0] = fmaf(bf2f(mv[0]), ev, mip[0]);
      mip[1] = fmaf(bf2f(mv[1]), ev, mip[1]);
      mip[2] = fmaf(bf2f(mv[2]), ev, mip[2]);
      mip[3] = fmaf(bf2f(mv[3]), ev, mip[3]);
    }
    atomicAdd(&mi_acc[i * M + c0 + 0], mip[0]);
    atomicAdd(&mi_acc[i * M + c0 + 1], mip[1]);
    atomicAdd(&mi_acc[i * M + c0 + 2], mip[2]);
    atomicAdd(&mi_acc[i * M + c0 + 3], mip[3]);
  }

  // ===== GEMM2: a2 = silu(m @ Wx0 + bx0) — epilogue after all A-reads, safe =====
#pragma unroll
  for (int nt = 0; nt < 16; ++nt) {
    const float b = bx0[nt * 16 + lnib];
    acc[nt] = (f32x4){b, b, b, b};
  }
  run_gemm(wsB + 65536);
#pragma unroll
  for (int nt = 0; nt < 16; ++nt)
#pragma unroll
    for (int reg = 0; reg < 4; ++reg) {
      const int row = r0 + quad * 4 + reg;
      a_act[row * PITCH + nt * 16 + lnib] = f2bf(silu_f(acc[nt][reg]));
    }

  // ===== GEMM3: a3 = silu(a2 @ Wx1 + bx1) =====
#pragma unroll
  for (int nt = 0; nt < 16; ++nt) {
    const float b = bx1[nt * 16 + lnib];
    acc[nt] = (f32x4){b, b, b, b};
  }
  run_gemm(wsB + 131072);
#pragma unroll
  for (int nt = 0; nt < 16; ++nt)
#pragma unroll
    for (int reg = 0; reg < 4; ++reg) {
      const int row = r0 + quad * 4 + reg;
      a_act[row * PITCH + nt * 16 + lnib] = f2bf(silu_f(acc[nt][reg]));
    }

  // ===== GEMM4: px = a3 @ Wxo + bxo (N padded to 16; cols 8..15 zero) =====
  // Tiny B (8 frags/wave) — read straight from global (L1/L2 hot).
  f32x4 px;
  {
    const float b = (lnib < 8) ? bxo[lnib] : 0.f;
    px = (f32x4){b, b, b, b};
    const unsigned short* B = wsB + 196608;
#pragma unroll
    for (int kt = 0; kt < 8; ++kt) {
      const v8bf a0 = *(const v8bf*)&a_act[(r0 + lnib) * PITCH + kt * 32 + quad * 8];
      const v8bf bv = *(const v8bf*)&B[(kt * 64 + lane) * 8];
      px = __builtin_amdgcn_mfma_f32_16x16x32_bf16(a0, bv, px, 0, 0, 0);
    }
  }

  // ===== shift: per-head normalized coordinate aggregation (wave-local) =====
  {
    const int hh = lnib & 7;   // lanes lnib>=8 hold zero px (padded B cols)
    const float xi0 = x[i * 24 + hh * 3 + 0];
    const float xi1 = x[i * 24 + hh * 3 + 1];
    const float xi2 = x[i * 24 + hh * 3 + 2];
    float p0 = 0.f, p1 = 0.f, p2 = 0.f;
#pragma unroll
    for (int reg = 0; reg < 4; ++reg) {
      const int row = r0 + quad * 4 + reg;
      const int jg = j0 + row;
      if (jg != i) {
        const float pxv = px[reg];
        const float sq  = s_sqn[row][hh];
        const float f   = pxv / (sqrtf(sq + 1e-8f) + 1.f);  // NORM_CONST=1
        p0 = fmaf(x[jg * 24 + hh * 3 + 0] - xi0, f, p0);
        p1 = fmaf(x[jg * 24 + hh * 3 + 1] - xi1, f, p1);
        p2 = fmaf(x[jg * 24 + hh * 3 + 2] - xi2, f, p2);
      }
    }
    p0 += __shfl_xor(p0, 16); p0 += __shfl_xor(p0, 32);
    p1 += __shfl_xor(p1, 16); p1 += __shfl_xor(p1, 32);
    p2 += __shfl_xor(p2, 16); p2 += __shfl_xor(p2, 32);
    if (lane < 8) {
      atomicAdd(&shift_acc[i * 24 + hh * 3 + 0], p0);
      atomicAdd(&shift_acc[i * 24 + hh * 3 + 1], p1);
      atomicAdd(&shift_acc[i * 24 + hh * 3 + 2], p2);
    }
  }
}

// ---------------------------------------------------------------------------
__global__ void k_xout(const float* __restrict__ x, const float* __restrict__ shift,
                       float* __restrict__ out)
{
  const int idx = blockIdx.x * 256 + threadIdx.x;
  if (idx < N_NODES * NH * 3) out[idx] = x[idx] + shift[idx] * (1.f / 511.f);
}

__global__ __launch_bounds__(256) void k_hout(
    const float* __restrict__ h, const float* __restrict__ mi,
    const float* __restrict__ Wh0, const float* __restrict__ bh0,
    const float* __restrict__ Wh1, const float* __restrict__ bh1,
    const float* __restrict__ Who, const float* __restrict__ bho,
    float* __restrict__ out)
{
  const int i = blockIdx.x, t = threadIdx.x;
  __shared__ float s_in[M + HD];
  __shared__ float s_b[M];
  s_in[t] = mi[i * M + t];
  if (t < HD) s_in[M + t] = h[i * HD + t];
  __syncthreads();
  float acc = bh0[t];
  for (int k = 0; k < M + HD; ++k) acc = fmaf(s_in[k], Wh0[k * M + t], acc);
  s_b[t] = silu_f(acc);
  __syncthreads();
  float acc2 = bh1[t];
  for (int k = 0; k < M; ++k) acc2 = fmaf(s_b[k], Wh1[k * M + t], acc2);
  const float a1v = silu_f(acc2);
  __syncthreads();
  s_in[t] = a1v;
  __syncthreads();
  if (t < HD) {
    float o = bho[t];
    for (int k = 0; k < M; ++k) o = fmaf(s_in[k], Who[k * HD + t], o);
    out[i * HD + t] = h[i * HD + t] + o;
  }
}

// ---------------------------------------------------------------------------
extern "C" void kernel_launch(void* const* d_in, const int* in_sizes, int n_in,
                              void* d_out, int out_size, void* d_ws, size_t ws_size,
                              hipStream_t stream)
{
  const float* x    = (const float*)d_in[0];
  const float* h    = (const float*)d_in[1];
  const float* We0  = (const float*)d_in[2];
  const float* be0  = (const float*)d_in[3];
  const float* We1  = (const float*)d_in[4];
  const float* be1  = (const float*)d_in[5];
  const float* Winf = (const float*)d_in[6];
  const float* binf = (const float*)d_in[7];
  const float* Wx0  = (const float*)d_in[8];
  const float* bx0  = (const float*)d_in[9];
  const float* Wx1  = (const float*)d_in[10];
  const float* bx1  = (const float*)d_in[11];
  const float* Wxo  = (const float*)d_in[12];
  const float* bxo  = (const float*)d_in[13];
  const float* Wh0  = (const float*)d_in[14];
  const float* bh0  = (const float*)d_in[15];
  const float* Wh1  = (const float*)d_in[16];
  const float* bh1  = (const float*)d_in[17];
  const float* Who  = (const float*)d_in[18];
  const float* bho  = (const float*)d_in[19];

  float* out_x = (float*)d_out;                 // [512,8,3]
  float* out_h = out_x + N_NODES * NH * 3;      // [512,128]

  // ws layout (float units): mi[131072] | shift[12288] | P[131072] | Q[131072] | wsB(bf16)
  float* ws    = (float*)d_ws;
  float* mi    = ws;
  float* shift = ws + 131072;
  float* P     = ws + 143360;
  float* Q     = ws + 274432;
  unsigned short* wsB = (unsigned short*)(ws + 405504);

  hipMemsetAsync(mi, 0, (131072 + 12288) * sizeof(float), stream);

  k_prep<<<784, 256, 0, stream>>>(We1, Wx0, Wx1, Wxo, wsB);
  k_pq<<<N_NODES, 256, 0, stream>>>(x, h, We0, P, Q);
  k_edge<<<dim3(N_NODES, N_NODES / JTILE), 256, 0, stream>>>(
      x, P, Q, We0, be0, be1, Winf, binf, bx0, bx1, bxo, wsB, mi, shift);
  k_xout<<<(N_NODES * NH * 3 + 255) / 256, 256, 0, stream>>>(x, shift, out_x);
  k_hout<<<N_NODES, 256, 0, stream>>>(h, mi, Wh0, bh0, Wh1, bh1, Who, bho, out_h);
}